// Round 3
// baseline (457.293 us; speedup 1.0000x reference)
//
#include <hip/hip_runtime.h>
#include <hip/hip_bf16.h>

// SCM_39676907888322: sigmoid-gated cross attention. fp32 I/O, bf16 MFMA compute.
// R7: attn occupancy restructure. R6 was latency-bound (2 waves/SIMD, nothing
// saturated). Now: 512-thr blocks, 8 waves = (ns 2) x (mq 4), m-split-4 with
// 32-row m-tiles. LDS 80 KB = K[4][32][128] + V[4][128][32] + Q[64][128]
// (Q in LDS frees 32 resident VGPRs) -> 2 blocks/CU = 4 waves/SIMD.
// Register diet for the forced 128-VGPR cap: single f32x16 S acc, 4+4 staging
// chunks, prefetch issued after QK^T. 2-round LDS reduction tree across mq.

typedef __bf16 bf16;
typedef __bf16 bf16x8 __attribute__((ext_vector_type(8)));
typedef __bf16 bf16x4 __attribute__((ext_vector_type(4)));
typedef float f32x4 __attribute__((ext_vector_type(4)));
typedef float f32x16 __attribute__((ext_vector_type(16)));
typedef unsigned int u32x4 __attribute__((ext_vector_type(4)));

#define NB 8
#define NC 256
#define NCI 128
#define NHW 2304
#define NT32 72    // 2304 / 32  (qkv n-tiles)

__global__ __launch_bounds__(256) void wconv_kernel(
    const float* __restrict__ w0, const float* __restrict__ w1,
    const float* __restrict__ w2, const float* __restrict__ w3,
    const float* __restrict__ w4, const float* __restrict__ w5,
    bf16* __restrict__ dst)
{
    int idx = (blockIdx.x * 256 + threadIdx.x) * 8;   // 6*32768 total
    int m = idx >> 15;                                 // matrix id (block-uniform)
    int off = idx & 32767;
    const float* w = (m == 0) ? w0 : (m == 1) ? w1 : (m == 2) ? w2
                   : (m == 3) ? w3 : (m == 4) ? w4 : w5;
    f32x4 a0 = *(const f32x4*)(w + off);
    f32x4 a1 = *(const f32x4*)(w + off + 4);
    bf16x8 o;
    #pragma unroll
    for (int j = 0; j < 4; ++j) { o[j] = (bf16)a0[j]; o[4 + j] = (bf16)a1[j]; }
    *(bf16x8*)(dst + idx) = o;
}

__global__ __launch_bounds__(256) void qkv_kernel(
    const float* __restrict__ x1, const float* __restrict__ x2,
    const bf16* __restrict__ wb,
    const float* __restrict__ bv1, const float* __restrict__ bk1, const float* __restrict__ bq1,
    const float* __restrict__ bv2, const float* __restrict__ bk2, const float* __restrict__ bq2,
    bf16* __restrict__ Qt, bf16* __restrict__ Kt, bf16* __restrict__ Vt,
    float* __restrict__ out)
{
    // Xt[n][c] bf16, 32 rows, padded stride 264
    __shared__ __align__(16) bf16 Xt[32 * 264];

    int gid = blockIdx.x;
    int nt = gid % NT32;
    int s = (gid / NT32) & 1;
    int b = gid / (2 * NT32);
    int n0 = nt * 32;

    const float* x = s ? x2 : x1;
    // wb layout: [v1,k1,q1,v2,k2,q2] each 128*256
    const bf16* wv = wb + (size_t)(s * 3 + 0) * (NCI * NC);
    const bf16* wk = wb + (size_t)(s * 3 + 1) * (NCI * NC);
    const bf16* wq = wb + (size_t)(s * 3 + 2) * (NCI * NC);
    const float* bv = s ? bv2 : bv1;
    const float* bk = s ? bk2 : bk1;
    const float* bq = s ? bq2 : bq1;
    float* outy = out + (size_t)s * (NB * 384 * NHW);

    int tid = threadIdx.x;
    // Stage X tile (256 c x 32 n) into LDS transposed (bf16); fp32 concat passthrough.
    {
        int n_off = (tid & 3) * 8;       // 0,8,16,24
        int c0l = tid >> 2;              // 0..63
        #pragma unroll
        for (int i = 0; i < 4; ++i) {
            int c = c0l + i * 64;
            const float* src = x + ((size_t)(b * NC + c) * NHW + n0 + n_off);
            f32x4 a0 = *(const f32x4*)src;
            f32x4 a1 = *(const f32x4*)(src + 4);
            float* dsty = outy + ((size_t)(b * 384 + c) * NHW + n0 + n_off);
            *(f32x4*)dsty = a0;
            *(f32x4*)(dsty + 4) = a1;
            #pragma unroll
            for (int j = 0; j < 4; ++j) {
                Xt[(n_off + j) * 264 + c] = (bf16)a0[j];
                Xt[(n_off + 4 + j) * 264 + c] = (bf16)a1[j];
            }
        }
    }
    __syncthreads();

    int lane = tid & 63;
    int wid = tid >> 6;                  // wave 0..3 -> ci strip of 32
    int row = lane & 15, quad = lane >> 4;
    int ci_base = wid * 32;

    f32x4 acc[3][2][2];                  // [q,k,v][mi][j]
    #pragma unroll
    for (int t = 0; t < 3; ++t)
        #pragma unroll
        for (int mi = 0; mi < 2; ++mi)
            #pragma unroll
            for (int j = 0; j < 2; ++j)
                acc[t][mi][j] = (f32x4){0.f, 0.f, 0.f, 0.f};

    const bf16* wptr[3] = {wq, wk, wv};
    #pragma unroll
    for (int ks = 0; ks < 8; ++ks) {
        int c0 = ks * 32 + quad * 8;
        bf16x8 bfrag[2];
        #pragma unroll
        for (int j = 0; j < 2; ++j)
            bfrag[j] = *(const bf16x8*)&Xt[(j * 16 + row) * 264 + c0];
        #pragma unroll
        for (int t = 0; t < 3; ++t) {
            #pragma unroll
            for (int mi = 0; mi < 2; ++mi) {
                bf16x8 afrag = *(const bf16x8*)&wptr[t][(size_t)(ci_base + mi * 16 + row) * NC + c0];
                #pragma unroll
                for (int j = 0; j < 2; ++j)
                    acc[t][mi][j] = __builtin_amdgcn_mfma_f32_16x16x32_bf16(
                        afrag, bfrag[j], acc[t][mi][j], 0, 0, 0);
            }
        }
    }

    // Epilogue: +bias (fp32), write Qt/Kt (n,128) bf16 8B stores, V (128,n) bf16 scalar.
    size_t qkbase = ((size_t)s * NB + b) * NHW * NCI;
    size_t vbase  = ((size_t)s * NB + b) * NCI * NHW;
    #pragma unroll
    for (int mi = 0; mi < 2; ++mi) {
        int ci0 = ci_base + mi * 16 + quad * 4;
        f32x4 bq4 = *(const f32x4*)&bq[ci0];
        f32x4 bk4 = *(const f32x4*)&bk[ci0];
        f32x4 bv4 = *(const f32x4*)&bv[ci0];
        #pragma unroll
        for (int j = 0; j < 2; ++j) {
            int n = n0 + j * 16 + row;   // D col = lane&15
            bf16x4 pk;
            #pragma unroll
            for (int r = 0; r < 4; ++r) pk[r] = (bf16)(acc[0][mi][j][r] + bq4[r]);
            *(bf16x4*)&Qt[qkbase + (size_t)n * NCI + ci0] = pk;
            #pragma unroll
            for (int r = 0; r < 4; ++r) pk[r] = (bf16)(acc[1][mi][j][r] + bk4[r]);
            *(bf16x4*)&Kt[qkbase + (size_t)n * NCI + ci0] = pk;
            #pragma unroll
            for (int r = 0; r < 4; ++r)
                Vt[vbase + (size_t)(ci0 + r) * NHW + n] = (bf16)(acc[2][mi][j][r] + bv4[r]);
        }
    }
}

__global__ __launch_bounds__(512, 4) void attn_kernel(
    const bf16* __restrict__ Qt, const bf16* __restrict__ Kt, const bf16* __restrict__ Vt,
    float* __restrict__ out)
{
    // SMEM 80 KB: KQ [4 mq][32 m][128 c] (chunk ^= row&15)
    //             VQ [4 mq][128 c][32 m] (chunk ^= (crow>>1)&3)
    //             QL [64 n][128 c]       (chunk ^= row&15)
    __shared__ __align__(16) bf16 SMEM[40960];
    bf16* KQ = SMEM;
    bf16* VQ = SMEM + 16384;
    bf16* QL = SMEM + 32768;

    int gid = blockIdx.x;
    // XCD swizzle: gid%8 = XCD slot; both dirs of batch b=gid%8 share an XCD.
    int pair = (gid & 7) * 2 + ((gid >> 3) & 1);   // 0..15
    int nb = gid >> 4;                              // 0..35
    int dir = pair & 1;
    int b = pair >> 1;

    int tid = threadIdx.x;
    int lane = tid & 63;
    int w = tid >> 6;
    int ns = w & 1;        // n-strip (32 rows within the 64-row block tile)
    int mq = w >> 1;       // m-quarter: m in [mq*576, mq*576+576)
    int col = lane & 31;
    int hi = lane >> 5;

    int sq = dir, skv = dir ^ 1;
    const bf16* q = Qt + ((size_t)sq  * NB + b) * (NHW * NCI);
    const bf16* k = Kt + ((size_t)skv * NB + b) * (NHW * NCI);
    const bf16* v = Vt + ((size_t)skv * NB + b) * (NCI * NHW);
    float* outy = out + (size_t)dir * (NB * 384 * NHW) + ((size_t)b * 384 + 256) * NHW;

    // Stage Q tile (64 n x 128 c) once; 1024 chunks over 512 threads.
    #pragma unroll
    for (int i = 0; i < 2; ++i) {
        int c = tid + i * 512;
        int qr = c >> 4, qc = c & 15;
        bf16x8 t = *(const bf16x8*)&q[(size_t)(nb * 64 + qr) * NCI + qc * 8];
        *(bf16x8*)&QL[qr * 128 + ((qc ^ (qr & 15)) * 8)] = t;
    }

    // Per-thread staging: 4 K-chunks + 4 V-chunks (16B each) per iter.
    // K: 4q x 32r x 16 chunks = 2048; V: 4q x 128c x 4 chunks = 2048.
    int kgoff[4], vgoff[4], kloff[4], vloff[4];
    #pragma unroll
    for (int i = 0; i < 4; ++i) {
        int c = tid + i * 512;
        int qd = c >> 9, cc = c & 511;
        int kr = cc >> 4, kc = cc & 15;
        kgoff[i] = (qd * 576 + kr) * NCI + kc * 8;
        kloff[i] = qd * 4096 + kr * 128 + ((kc ^ (kr & 15)) * 8);
        int vr = cc >> 2, vc = cc & 3;
        vgoff[i] = vr * NHW + qd * 576 + vc * 8;
        vloff[i] = qd * 4096 + vr * 32 + ((vc ^ ((vr >> 1) & 3)) * 8);
    }

    int nw = nb * 64 + ns * 32;          // this wave's 32 Q rows

    f32x16 o0, o1, o2, o3;               // O^T acc: c-tiles 0..3 (static only)
    #pragma unroll
    for (int j = 0; j < 16; ++j) { o0[j] = 0.f; o1[j] = 0.f; o2[j] = 0.f; o3[j] = 0.f; }

    // Prefetch tile 0 into registers.
    bf16x8 rk[4], rv[4];
    #pragma unroll
    for (int i = 0; i < 4; ++i) {
        rk[i] = *(const bf16x8*)(k + kgoff[i]);
        rv[i] = *(const bf16x8*)(v + vgoff[i]);
    }

    // Hoisted read-address pieces.
    int krd = mq * 4096 + col * 128;     // K row base (this wave's quarter)
    int qrd = (ns * 32 + col) * 128;     // Q row base
    int cswz = col & 15;
    int vsw = (col >> 1) & 3;
    int vrd = mq * 4096 + col * 32;      // V row base (+ ct*32*32)

    for (int it = 0; it < 18; ++it) {
        __syncthreads();                 // prior tile's LDS reads complete
        #pragma unroll
        for (int i = 0; i < 4; ++i) {
            *(bf16x8*)&KQ[kloff[i]] = rk[i];
            *(bf16x8*)&VQ[vloff[i]] = rv[i];
        }
        __syncthreads();                 // tile it visible to all waves

        // S^T = K * Q^T : 32 m-rows x 32 n-cols (swapped operands)
        f32x16 s;
        #pragma unroll
        for (int j = 0; j < 16; ++j) s[j] = 0.f;

        __builtin_amdgcn_s_setprio(1);
        #pragma unroll
        for (int kq = 0; kq < 8; ++kq) {
            int ch = ((2 * kq + hi) ^ cswz) * 8;
            bf16x8 kf = *(const bf16x8*)&KQ[krd + ch];
            bf16x8 qf = *(const bf16x8*)&QL[qrd + ch];
            s = __builtin_amdgcn_mfma_f32_32x32x16_bf16(kf, qf, s, 0, 0, 0);
        }
        __builtin_amdgcn_s_setprio(0);

        if (it < 17) {                   // prefetch it+1 (hidden under sigmoid+PV+TLP)
            size_t ko = (size_t)(it + 1) * 4096;
            int vo = (it + 1) * 32;
            #pragma unroll
            for (int i = 0; i < 4; ++i) {
                rk[i] = *(const bf16x8*)(k + ko + kgoff[i]);
                rv[i] = *(const bf16x8*)(v + vo + vgoff[i]);
            }
        }

        // sigmoid (in-register) -> bf16 PV B-frags via cvt_pk + permlane32_swap.
        // S^T C-layout: reg r = S^T[m = (r&3)+8*(r>>2)+4*hi][n = col].
        // PV B-frag (k-chunk km): elem t = P^T[m = km*16 + 8*hi_dest + t][col].
        float p[16];
        #pragma unroll
        for (int r = 0; r < 16; ++r) {
            float e = __expf(-s[r]);
            p[r] = __builtin_amdgcn_rcpf(1.0f + e);
        }
        u32x4 pbw[2];
        #pragma unroll
        for (int kst = 0; kst < 2; ++kst) {
            unsigned int a0, a1, b0, b1;
            asm("v_cvt_pk_bf16_f32 %0, %1, %2" : "=v"(a0) : "v"(p[8*kst+0]), "v"(p[8*kst+1]));
            asm("v_cvt_pk_bf16_f32 %0, %1, %2" : "=v"(a1) : "v"(p[8*kst+2]), "v"(p[8*kst+3]));
            asm("v_cvt_pk_bf16_f32 %0, %1, %2" : "=v"(b0) : "v"(p[8*kst+4]), "v"(p[8*kst+5]));
            asm("v_cvt_pk_bf16_f32 %0, %1, %2" : "=v"(b1) : "v"(p[8*kst+6]), "v"(p[8*kst+7]));
            // swap32: a' = {a[0:31], b[0:31]}, b' = {a[32:63], b[32:63]}
            asm volatile("v_permlane32_swap_b32 %0, %1" : "+v"(a0), "+v"(b0));
            asm volatile("v_permlane32_swap_b32 %0, %1" : "+v"(a1), "+v"(b1));
            pbw[kst] = (u32x4){a0, a1, b0, b1};
        }

        // O^T += V * P^T (V from LDS as A-frags)
        __builtin_amdgcn_s_setprio(1);
        #pragma unroll
        for (int km = 0; km < 2; ++km) {
            bf16x8 pf = __builtin_bit_cast(bf16x8, pbw[km]);
            int mch = ((2 * km + hi) ^ vsw) * 8;
            {
                bf16x8 vf = *(const bf16x8*)&VQ[vrd + 0 * 1024 + mch];
                o0 = __builtin_amdgcn_mfma_f32_32x32x16_bf16(vf, pf, o0, 0, 0, 0);
            }
            {
                bf16x8 vf = *(const bf16x8*)&VQ[vrd + 1 * 1024 + mch];
                o1 = __builtin_amdgcn_mfma_f32_32x32x16_bf16(vf, pf, o1, 0, 0, 0);
            }
            {
                bf16x8 vf = *(const bf16x8*)&VQ[vrd + 2 * 1024 + mch];
                o2 = __builtin_amdgcn_mfma_f32_32x32x16_bf16(vf, pf, o2, 0, 0, 0);
            }
            {
                bf16x8 vf = *(const bf16x8*)&VQ[vrd + 3 * 1024 + mch];
                o3 = __builtin_amdgcn_mfma_f32_32x32x16_bf16(vf, pf, o3, 0, 0, 0);
            }
        }
        __builtin_amdgcn_s_setprio(0);
    }

    // 2-round reduction across mq (4-way) via LDS; all o indices compile-time,
    // mq branches wave-uniform, barriers at block scope.
    float* RED = (float*)SMEM;           // 4 bufs x 16 KB (round 1), 2 bufs (round 2)

    auto wpart = [&](float* buf, const f32x16& a, int cb) {
        #pragma unroll
        for (int g = 0; g < 4; ++g) {
            f32x4 v4;
            #pragma unroll
            for (int j = 0; j < 4; ++j) v4[j] = a[g * 4 + j];
            *(f32x4*)&buf[lane * 64 + (((cb * 4 + g) ^ (lane & 15)) * 4)] = v4;
        }
    };
    auto rpart = [&](float* buf, f32x16& a, int cb) {
        #pragma unroll
        for (int g = 0; g < 4; ++g) {
            f32x4 v4 = *(const f32x4*)&buf[lane * 64 + (((cb * 4 + g) ^ (lane & 15)) * 4)];
            #pragma unroll
            for (int j = 0; j < 4; ++j) a[g * 4 + j] += v4[j];
        }
    };

    __syncthreads();
    if (mq >= 2) {
        float* buf = RED + (ns * 2 + (mq & 1)) * 4096;
        wpart(buf, o0, 0); wpart(buf, o1, 1); wpart(buf, o2, 2); wpart(buf, o3, 3);
    }
    __syncthreads();
    if (mq < 2) {
        float* buf = RED + (ns * 2 + mq) * 4096;
        rpart(buf, o0, 0); rpart(buf, o1, 1); rpart(buf, o2, 2); rpart(buf, o3, 3);
    }
    __syncthreads();
    if (mq == 1) {
        float* buf = RED + ns * 4096;
        wpart(buf, o0, 0); wpart(buf, o1, 1); wpart(buf, o2, 2); wpart(buf, o3, 3);
    }
    __syncthreads();
    if (mq == 0) {
        float* buf = RED + ns * 4096;
        rpart(buf, o0, 0); rpart(buf, o1, 1); rpart(buf, o2, 2); rpart(buf, o3, 3);
        #pragma unroll
        for (int r = 0; r < 16; ++r) {
            int cr = (r & 3) + 8 * (r >> 2) + 4 * hi;
            outy[(size_t)(0 * 32 + cr) * NHW + nw + col] = o0[r];
            outy[(size_t)(1 * 32 + cr) * NHW + nw + col] = o1[r];
            outy[(size_t)(2 * 32 + cr) * NHW + nw + col] = o2[r];
            outy[(size_t)(3 * 32 + cr) * NHW + nw + col] = o3[r];
        }
    }
}

extern "C" void kernel_launch(void* const* d_in, const int* in_sizes, int n_in,
                              void* d_out, int out_size, void* d_ws, size_t ws_size,
                              hipStream_t stream) {
    const float* x1  = (const float*)d_in[0];
    const float* x2  = (const float*)d_in[1];
    const float* wv1 = (const float*)d_in[2];  const float* bv1 = (const float*)d_in[3];
    const float* wk1 = (const float*)d_in[4];  const float* bk1 = (const float*)d_in[5];
    const float* wq1 = (const float*)d_in[6];  const float* bq1 = (const float*)d_in[7];
    const float* wv2 = (const float*)d_in[8];  const float* bv2 = (const float*)d_in[9];
    const float* wk2 = (const float*)d_in[10]; const float* bk2 = (const float*)d_in[11];
    const float* wq2 = (const float*)d_in[12]; const float* bq2 = (const float*)d_in[13];
    float* out = (float*)d_out;

    // ws layout (bf16): Qt[2][B][2304][128] | Kt | Vt[2][B][128][2304] | wb[6][128*256]
    size_t per = (size_t)2 * NB * NHW * NCI;
    bf16* Qt = (bf16*)d_ws;
    bf16* Kt = Qt + per;
    bf16* Vt = Kt + per;
    bf16* wb = Vt + per;

    wconv_kernel<<<dim3(96), dim3(256), 0, stream>>>(wv1, wk1, wq1, wv2, wk2, wq2, wb);

    qkv_kernel<<<dim3(NB * 2 * NT32), dim3(256), 0, stream>>>(
        x1, x2, wb, bv1, bk1, bq1, bv2, bk2, bq2, Qt, Kt, Vt, out);

    attn_kernel<<<dim3(NB * 2 * 36), dim3(512), 0, stream>>>(Qt, Kt, Vt, out);
}

// Round 4
// 244.053 us; speedup vs baseline: 1.8737x; 1.8737x over previous
//
#include <hip/hip_runtime.h>
#include <hip/hip_bf16.h>

// SCM_39676907888322: sigmoid-gated cross attention. fp32 I/O, bf16 MFMA compute.
// R8: R7 structure (512-thr, 8 waves = 2 ns x 4 mq, 32-row m-tiles, Q in LDS,
// in-register P) with the VGPR catastrophe fixed:
//  - __launch_bounds__(512,2): empirically arg*block-waves = waves/CU, so
//    (512,4) capped VGPR at 2048/32 = 64 -> full accumulator spill (R7's
//    424 MB scratch writes). (512,2) -> 16 waves/CU -> 128-reg cap.
//  - prefetch moved AFTER the P-frag build so s (16 regs) is dead before
//    rk/rv (16 regs) go live: peak ~112 VGPR, fits the cap either way.

typedef __bf16 bf16;
typedef __bf16 bf16x8 __attribute__((ext_vector_type(8)));
typedef __bf16 bf16x4 __attribute__((ext_vector_type(4)));
typedef float f32x4 __attribute__((ext_vector_type(4)));
typedef float f32x16 __attribute__((ext_vector_type(16)));
typedef unsigned int u32x4 __attribute__((ext_vector_type(4)));

#define NB 8
#define NC 256
#define NCI 128
#define NHW 2304
#define NT32 72    // 2304 / 32  (qkv n-tiles)

__global__ __launch_bounds__(256) void wconv_kernel(
    const float* __restrict__ w0, const float* __restrict__ w1,
    const float* __restrict__ w2, const float* __restrict__ w3,
    const float* __restrict__ w4, const float* __restrict__ w5,
    bf16* __restrict__ dst)
{
    int idx = (blockIdx.x * 256 + threadIdx.x) * 8;   // 6*32768 total
    int m = idx >> 15;                                 // matrix id (block-uniform)
    int off = idx & 32767;
    const float* w = (m == 0) ? w0 : (m == 1) ? w1 : (m == 2) ? w2
                   : (m == 3) ? w3 : (m == 4) ? w4 : w5;
    f32x4 a0 = *(const f32x4*)(w + off);
    f32x4 a1 = *(const f32x4*)(w + off + 4);
    bf16x8 o;
    #pragma unroll
    for (int j = 0; j < 4; ++j) { o[j] = (bf16)a0[j]; o[4 + j] = (bf16)a1[j]; }
    *(bf16x8*)(dst + idx) = o;
}

__global__ __launch_bounds__(256) void qkv_kernel(
    const float* __restrict__ x1, const float* __restrict__ x2,
    const bf16* __restrict__ wb,
    const float* __restrict__ bv1, const float* __restrict__ bk1, const float* __restrict__ bq1,
    const float* __restrict__ bv2, const float* __restrict__ bk2, const float* __restrict__ bq2,
    bf16* __restrict__ Qt, bf16* __restrict__ Kt, bf16* __restrict__ Vt,
    float* __restrict__ out)
{
    // Xt[n][c] bf16, 32 rows, padded stride 264
    __shared__ __align__(16) bf16 Xt[32 * 264];

    int gid = blockIdx.x;
    int nt = gid % NT32;
    int s = (gid / NT32) & 1;
    int b = gid / (2 * NT32);
    int n0 = nt * 32;

    const float* x = s ? x2 : x1;
    // wb layout: [v1,k1,q1,v2,k2,q2] each 128*256
    const bf16* wv = wb + (size_t)(s * 3 + 0) * (NCI * NC);
    const bf16* wk = wb + (size_t)(s * 3 + 1) * (NCI * NC);
    const bf16* wq = wb + (size_t)(s * 3 + 2) * (NCI * NC);
    const float* bv = s ? bv2 : bv1;
    const float* bk = s ? bk2 : bk1;
    const float* bq = s ? bq2 : bq1;
    float* outy = out + (size_t)s * (NB * 384 * NHW);

    int tid = threadIdx.x;
    // Stage X tile (256 c x 32 n) into LDS transposed (bf16); fp32 concat passthrough.
    {
        int n_off = (tid & 3) * 8;       // 0,8,16,24
        int c0l = tid >> 2;              // 0..63
        #pragma unroll
        for (int i = 0; i < 4; ++i) {
            int c = c0l + i * 64;
            const float* src = x + ((size_t)(b * NC + c) * NHW + n0 + n_off);
            f32x4 a0 = *(const f32x4*)src;
            f32x4 a1 = *(const f32x4*)(src + 4);
            float* dsty = outy + ((size_t)(b * 384 + c) * NHW + n0 + n_off);
            *(f32x4*)dsty = a0;
            *(f32x4*)(dsty + 4) = a1;
            #pragma unroll
            for (int j = 0; j < 4; ++j) {
                Xt[(n_off + j) * 264 + c] = (bf16)a0[j];
                Xt[(n_off + 4 + j) * 264 + c] = (bf16)a1[j];
            }
        }
    }
    __syncthreads();

    int lane = tid & 63;
    int wid = tid >> 6;                  // wave 0..3 -> ci strip of 32
    int row = lane & 15, quad = lane >> 4;
    int ci_base = wid * 32;

    f32x4 acc[3][2][2];                  // [q,k,v][mi][j]
    #pragma unroll
    for (int t = 0; t < 3; ++t)
        #pragma unroll
        for (int mi = 0; mi < 2; ++mi)
            #pragma unroll
            for (int j = 0; j < 2; ++j)
                acc[t][mi][j] = (f32x4){0.f, 0.f, 0.f, 0.f};

    const bf16* wptr[3] = {wq, wk, wv};
    #pragma unroll
    for (int ks = 0; ks < 8; ++ks) {
        int c0 = ks * 32 + quad * 8;
        bf16x8 bfrag[2];
        #pragma unroll
        for (int j = 0; j < 2; ++j)
            bfrag[j] = *(const bf16x8*)&Xt[(j * 16 + row) * 264 + c0];
        #pragma unroll
        for (int t = 0; t < 3; ++t) {
            #pragma unroll
            for (int mi = 0; mi < 2; ++mi) {
                bf16x8 afrag = *(const bf16x8*)&wptr[t][(size_t)(ci_base + mi * 16 + row) * NC + c0];
                #pragma unroll
                for (int j = 0; j < 2; ++j)
                    acc[t][mi][j] = __builtin_amdgcn_mfma_f32_16x16x32_bf16(
                        afrag, bfrag[j], acc[t][mi][j], 0, 0, 0);
            }
        }
    }

    // Epilogue: +bias (fp32), write Qt/Kt (n,128) bf16 8B stores, V (128,n) bf16 scalar.
    size_t qkbase = ((size_t)s * NB + b) * NHW * NCI;
    size_t vbase  = ((size_t)s * NB + b) * NCI * NHW;
    #pragma unroll
    for (int mi = 0; mi < 2; ++mi) {
        int ci0 = ci_base + mi * 16 + quad * 4;
        f32x4 bq4 = *(const f32x4*)&bq[ci0];
        f32x4 bk4 = *(const f32x4*)&bk[ci0];
        f32x4 bv4 = *(const f32x4*)&bv[ci0];
        #pragma unroll
        for (int j = 0; j < 2; ++j) {
            int n = n0 + j * 16 + row;   // D col = lane&15
            bf16x4 pk;
            #pragma unroll
            for (int r = 0; r < 4; ++r) pk[r] = (bf16)(acc[0][mi][j][r] + bq4[r]);
            *(bf16x4*)&Qt[qkbase + (size_t)n * NCI + ci0] = pk;
            #pragma unroll
            for (int r = 0; r < 4; ++r) pk[r] = (bf16)(acc[1][mi][j][r] + bk4[r]);
            *(bf16x4*)&Kt[qkbase + (size_t)n * NCI + ci0] = pk;
            #pragma unroll
            for (int r = 0; r < 4; ++r)
                Vt[vbase + (size_t)(ci0 + r) * NHW + n] = (bf16)(acc[2][mi][j][r] + bv4[r]);
        }
    }
}

__global__ __launch_bounds__(512, 2) void attn_kernel(
    const bf16* __restrict__ Qt, const bf16* __restrict__ Kt, const bf16* __restrict__ Vt,
    float* __restrict__ out)
{
    // SMEM 80 KB: KQ [4 mq][32 m][128 c] (chunk ^= row&15)
    //             VQ [4 mq][128 c][32 m] (chunk ^= (crow>>1)&3)
    //             QL [64 n][128 c]       (chunk ^= row&15)
    __shared__ __align__(16) bf16 SMEM[40960];
    bf16* KQ = SMEM;
    bf16* VQ = SMEM + 16384;
    bf16* QL = SMEM + 32768;

    int gid = blockIdx.x;
    // XCD swizzle: gid%8 = XCD slot; both dirs of batch b=gid%8 share an XCD.
    int pair = (gid & 7) * 2 + ((gid >> 3) & 1);   // 0..15
    int nb = gid >> 4;                              // 0..35
    int dir = pair & 1;
    int b = pair >> 1;

    int tid = threadIdx.x;
    int lane = tid & 63;
    int w = tid >> 6;
    int ns = w & 1;        // n-strip (32 rows within the 64-row block tile)
    int mq = w >> 1;       // m-quarter: m in [mq*576, mq*576+576)
    int col = lane & 31;
    int hi = lane >> 5;

    int sq = dir, skv = dir ^ 1;
    const bf16* q = Qt + ((size_t)sq  * NB + b) * (NHW * NCI);
    const bf16* k = Kt + ((size_t)skv * NB + b) * (NHW * NCI);
    const bf16* v = Vt + ((size_t)skv * NB + b) * (NCI * NHW);
    float* outy = out + (size_t)dir * (NB * 384 * NHW) + ((size_t)b * 384 + 256) * NHW;

    // Stage Q tile (64 n x 128 c) once; 1024 chunks over 512 threads.
    #pragma unroll
    for (int i = 0; i < 2; ++i) {
        int c = tid + i * 512;
        int qr = c >> 4, qc = c & 15;
        bf16x8 t = *(const bf16x8*)&q[(size_t)(nb * 64 + qr) * NCI + qc * 8];
        *(bf16x8*)&QL[qr * 128 + ((qc ^ (qr & 15)) * 8)] = t;
    }

    // Per-thread staging: 4 K-chunks + 4 V-chunks (16B each) per iter.
    // K: 4q x 32r x 16 chunks = 2048; V: 4q x 128c x 4 chunks = 2048.
    int kgoff[4], vgoff[4], kloff[4], vloff[4];
    #pragma unroll
    for (int i = 0; i < 4; ++i) {
        int c = tid + i * 512;
        int qd = c >> 9, cc = c & 511;
        int kr = cc >> 4, kc = cc & 15;
        kgoff[i] = (qd * 576 + kr) * NCI + kc * 8;
        kloff[i] = qd * 4096 + kr * 128 + ((kc ^ (kr & 15)) * 8);
        int vr = cc >> 2, vc = cc & 3;
        vgoff[i] = vr * NHW + qd * 576 + vc * 8;
        vloff[i] = qd * 4096 + vr * 32 + ((vc ^ ((vr >> 1) & 3)) * 8);
    }

    int nw = nb * 64 + ns * 32;          // this wave's 32 Q rows

    f32x16 o0, o1, o2, o3;               // O^T acc: c-tiles 0..3 (static only)
    #pragma unroll
    for (int j = 0; j < 16; ++j) { o0[j] = 0.f; o1[j] = 0.f; o2[j] = 0.f; o3[j] = 0.f; }

    // Prefetch tile 0 into registers.
    bf16x8 rk[4], rv[4];
    #pragma unroll
    for (int i = 0; i < 4; ++i) {
        rk[i] = *(const bf16x8*)(k + kgoff[i]);
        rv[i] = *(const bf16x8*)(v + vgoff[i]);
    }

    // Hoisted read-address pieces.
    int krd = mq * 4096 + col * 128;     // K row base (this wave's quarter)
    int qrd = (ns * 32 + col) * 128;     // Q row base
    int cswz = col & 15;
    int vsw = (col >> 1) & 3;
    int vrd = mq * 4096 + col * 32;      // V row base (+ ct*32*32)

    for (int it = 0; it < 18; ++it) {
        __syncthreads();                 // prior tile's LDS reads complete
        #pragma unroll
        for (int i = 0; i < 4; ++i) {
            *(bf16x8*)&KQ[kloff[i]] = rk[i];
            *(bf16x8*)&VQ[vloff[i]] = rv[i];
        }
        __syncthreads();                 // tile it visible to all waves

        // S^T = K * Q^T : 32 m-rows x 32 n-cols (swapped operands)
        f32x16 s;
        #pragma unroll
        for (int j = 0; j < 16; ++j) s[j] = 0.f;

        __builtin_amdgcn_s_setprio(1);
        #pragma unroll
        for (int kq = 0; kq < 8; ++kq) {
            int ch = ((2 * kq + hi) ^ cswz) * 8;
            bf16x8 kf = *(const bf16x8*)&KQ[krd + ch];
            bf16x8 qf = *(const bf16x8*)&QL[qrd + ch];
            s = __builtin_amdgcn_mfma_f32_32x32x16_bf16(kf, qf, s, 0, 0, 0);
        }
        __builtin_amdgcn_s_setprio(0);

        // sigmoid (in-register) -> bf16 PV B-frags via cvt_pk + permlane32_swap.
        // S^T C-layout: reg r = S^T[m = (r&3)+8*(r>>2)+4*hi][n = col].
        // PV B-frag (k-chunk km): elem t = P^T[m = km*16 + 8*hi_dest + t][col].
        float p[16];
        #pragma unroll
        for (int r = 0; r < 16; ++r) {
            float e = __expf(-s[r]);
            p[r] = __builtin_amdgcn_rcpf(1.0f + e);
        }
        u32x4 pbw[2];
        #pragma unroll
        for (int kst = 0; kst < 2; ++kst) {
            unsigned int a0, a1, b0, b1;
            asm("v_cvt_pk_bf16_f32 %0, %1, %2" : "=v"(a0) : "v"(p[8*kst+0]), "v"(p[8*kst+1]));
            asm("v_cvt_pk_bf16_f32 %0, %1, %2" : "=v"(a1) : "v"(p[8*kst+2]), "v"(p[8*kst+3]));
            asm("v_cvt_pk_bf16_f32 %0, %1, %2" : "=v"(b0) : "v"(p[8*kst+4]), "v"(p[8*kst+5]));
            asm("v_cvt_pk_bf16_f32 %0, %1, %2" : "=v"(b1) : "v"(p[8*kst+6]), "v"(p[8*kst+7]));
            // swap32: a' = {a[0:31], b[0:31]}, b' = {a[32:63], b[32:63]}
            asm volatile("v_permlane32_swap_b32 %0, %1" : "+v"(a0), "+v"(b0));
            asm volatile("v_permlane32_swap_b32 %0, %1" : "+v"(a1), "+v"(b1));
            pbw[kst] = (u32x4){a0, a1, b0, b1};
        }

        // Prefetch it+1 AFTER s/p are dead (peak-VGPR control); PV + next-iter
        // barrier cover the (L2-resident) latency.
        if (it < 17) {
            size_t ko = (size_t)(it + 1) * 4096;
            int vo = (it + 1) * 32;
            #pragma unroll
            for (int i = 0; i < 4; ++i) {
                rk[i] = *(const bf16x8*)(k + ko + kgoff[i]);
                rv[i] = *(const bf16x8*)(v + vo + vgoff[i]);
            }
        }

        // O^T += V * P^T (V from LDS as A-frags)
        __builtin_amdgcn_s_setprio(1);
        #pragma unroll
        for (int km = 0; km < 2; ++km) {
            bf16x8 pf = __builtin_bit_cast(bf16x8, pbw[km]);
            int mch = ((2 * km + hi) ^ vsw) * 8;
            {
                bf16x8 vf = *(const bf16x8*)&VQ[vrd + 0 * 1024 + mch];
                o0 = __builtin_amdgcn_mfma_f32_32x32x16_bf16(vf, pf, o0, 0, 0, 0);
            }
            {
                bf16x8 vf = *(const bf16x8*)&VQ[vrd + 1 * 1024 + mch];
                o1 = __builtin_amdgcn_mfma_f32_32x32x16_bf16(vf, pf, o1, 0, 0, 0);
            }
            {
                bf16x8 vf = *(const bf16x8*)&VQ[vrd + 2 * 1024 + mch];
                o2 = __builtin_amdgcn_mfma_f32_32x32x16_bf16(vf, pf, o2, 0, 0, 0);
            }
            {
                bf16x8 vf = *(const bf16x8*)&VQ[vrd + 3 * 1024 + mch];
                o3 = __builtin_amdgcn_mfma_f32_32x32x16_bf16(vf, pf, o3, 0, 0, 0);
            }
        }
        __builtin_amdgcn_s_setprio(0);
    }

    // 2-round reduction across mq (4-way) via LDS; all o indices compile-time,
    // mq branches wave-uniform, barriers at block scope.
    float* RED = (float*)SMEM;           // 4 bufs x 16 KB (round 1), 2 bufs (round 2)

    auto wpart = [&](float* buf, const f32x16& a, int cb) {
        #pragma unroll
        for (int g = 0; g < 4; ++g) {
            f32x4 v4;
            #pragma unroll
            for (int j = 0; j < 4; ++j) v4[j] = a[g * 4 + j];
            *(f32x4*)&buf[lane * 64 + (((cb * 4 + g) ^ (lane & 15)) * 4)] = v4;
        }
    };
    auto rpart = [&](float* buf, f32x16& a, int cb) {
        #pragma unroll
        for (int g = 0; g < 4; ++g) {
            f32x4 v4 = *(const f32x4*)&buf[lane * 64 + (((cb * 4 + g) ^ (lane & 15)) * 4)];
            #pragma unroll
            for (int j = 0; j < 4; ++j) a[g * 4 + j] += v4[j];
        }
    };

    __syncthreads();
    if (mq >= 2) {
        float* buf = RED + (ns * 2 + (mq & 1)) * 4096;
        wpart(buf, o0, 0); wpart(buf, o1, 1); wpart(buf, o2, 2); wpart(buf, o3, 3);
    }
    __syncthreads();
    if (mq < 2) {
        float* buf = RED + (ns * 2 + mq) * 4096;
        rpart(buf, o0, 0); rpart(buf, o1, 1); rpart(buf, o2, 2); rpart(buf, o3, 3);
    }
    __syncthreads();
    if (mq == 1) {
        float* buf = RED + ns * 4096;
        wpart(buf, o0, 0); wpart(buf, o1, 1); wpart(buf, o2, 2); wpart(buf, o3, 3);
    }
    __syncthreads();
    if (mq == 0) {
        float* buf = RED + ns * 4096;
        rpart(buf, o0, 0); rpart(buf, o1, 1); rpart(buf, o2, 2); rpart(buf, o3, 3);
        #pragma unroll
        for (int r = 0; r < 16; ++r) {
            int cr = (r & 3) + 8 * (r >> 2) + 4 * hi;
            outy[(size_t)(0 * 32 + cr) * NHW + nw + col] = o0[r];
            outy[(size_t)(1 * 32 + cr) * NHW + nw + col] = o1[r];
            outy[(size_t)(2 * 32 + cr) * NHW + nw + col] = o2[r];
            outy[(size_t)(3 * 32 + cr) * NHW + nw + col] = o3[r];
        }
    }
}

extern "C" void kernel_launch(void* const* d_in, const int* in_sizes, int n_in,
                              void* d_out, int out_size, void* d_ws, size_t ws_size,
                              hipStream_t stream) {
    const float* x1  = (const float*)d_in[0];
    const float* x2  = (const float*)d_in[1];
    const float* wv1 = (const float*)d_in[2];  const float* bv1 = (const float*)d_in[3];
    const float* wk1 = (const float*)d_in[4];  const float* bk1 = (const float*)d_in[5];
    const float* wq1 = (const float*)d_in[6];  const float* bq1 = (const float*)d_in[7];
    const float* wv2 = (const float*)d_in[8];  const float* bv2 = (const float*)d_in[9];
    const float* wk2 = (const float*)d_in[10]; const float* bk2 = (const float*)d_in[11];
    const float* wq2 = (const float*)d_in[12]; const float* bq2 = (const float*)d_in[13];
    float* out = (float*)d_out;

    // ws layout (bf16): Qt[2][B][2304][128] | Kt | Vt[2][B][128][2304] | wb[6][128*256]
    size_t per = (size_t)2 * NB * NHW * NCI;
    bf16* Qt = (bf16*)d_ws;
    bf16* Kt = Qt + per;
    bf16* Vt = Kt + per;
    bf16* wb = Vt + per;

    wconv_kernel<<<dim3(96), dim3(256), 0, stream>>>(wv1, wk1, wq1, wv2, wk2, wq2, wb);

    qkv_kernel<<<dim3(NB * 2 * NT32), dim3(256), 0, stream>>>(
        x1, x2, wb, bv1, bk1, bq1, bv2, bk2, bq2, Qt, Kt, Vt, out);

    attn_kernel<<<dim3(NB * 2 * 36), dim3(512), 0, stream>>>(Qt, Kt, Vt, out);
}